// Round 10
// baseline (234.477 us; speedup 1.0000x reference)
//
#include <hip/hip_runtime.h>

// Problem constants (fixed by the reference file)
#define BATCH   8
#define C_OUT_N 96
#define NK      11
#define C_IN_N  1056      // C_OUT_N * NK
#define GRP     4
#define HOUT    56
#define WOUT    56
#define HIN     60
#define WIN     60
#define EP      2

#define CH_DW   (HIN * WIN)   // 3600 dwords per channel
#define ROWS_PW 7             // 8 waves x 7 rows = 56 output rows

// r10: NO LDS. Every access in this op is row-coalesced (lanes contiguous,
// wave-uniform row/col shifts), and the active working set per block is one
// 14.4 KB channel -> L1-resident. Loads go straight to L1/L2 via
// SGPR-base + imm-offset global loads. Zero barriers, zero staging, waves
// fully independent; the vmem pipe (idle in the LDS variant) does the work
// the LDS pipe+barrier convoys did, without the ~20-30 us structural
// overhead the r7-r9 nulls localized to the staging machinery.
__global__ __launch_bounds__(512, 3) void addshift_kernel(
    const float* __restrict__ x,
    const float* __restrict__ w1,
    const float* __restrict__ w2,
    const float* __restrict__ w3,
    const int*   __restrict__ pad_hv,       // (C_IN, 8)
    const int*   __restrict__ idx_identit,  // (C_OUT, 4)
    float* __restrict__ out)                // [out_h | out_v | out_i]
{
    const int co  = blockIdx.x;
    const int b   = blockIdx.y;
    const int tid = threadIdx.x;

    const int wave = tid >> 6;
    const int w    = tid & 63;
    const int wc   = (w < WOUT) ? w : (WOUT - 1);    // clamp idle lanes
    const int h0   = __builtin_amdgcn_readfirstlane(wave * ROWS_PW); // scalar
    const int cV   = wc + EP;                        // V/I column, always valid

    // ---- Lane-distributed parameter preload: lane l = g*NK + k (l < 44)
    // holds {ph, pv, a1, a2}; per-k access is v_readlane (k uniform).
    int   myPh = 0, myPv = 0;
    float myA1 = 0.f, myA2 = 0.f;
    if (w < GRP * NK) {
        const int lg = w / NK;
        const int lk = w - lg * NK;
        const int lc = co * NK + lk;
        myPh = pad_hv[lc * 8 + lg];
        myPv = pad_hv[lc * 8 + 4 + lg];
        myA1 = w1[lg * C_IN_N + lc];
        myA2 = w2[lg * C_IN_N + lc];
    }

    // Block-uniform identity-gather info
    int   kI[GRP];
    float w3v[GRP];
#pragma unroll
    for (int g = 0; g < GRP; ++g) {
        kI[g]  = idx_identit[co * GRP + g] - co * NK;   // in [0, NK)
        w3v[g] = w3[g * C_OUT_N + co];
    }

    float accH[ROWS_PW], accV[ROWS_PW], accI[ROWS_PW];
#pragma unroll
    for (int i = 0; i < ROWS_PW; ++i) { accH[i] = 0.f; accV[i] = 0.f; accI[i] = 0.f; }

    const float* chan_base = x + ((size_t)b * C_IN_N + (size_t)co * NK) * CH_DW;

#pragma unroll 1
    for (int k = 0; k < NK; ++k) {
        const float* __restrict__ ch = chan_base + (size_t)k * CH_DW;

        // Per-channel params via register broadcast -- zero memory latency.
        int ph[GRP], pv[GRP];
        float a1[GRP], a2[GRP];
#pragma unroll
        for (int g = 0; g < GRP; ++g) {
            const int src = g * NK + k;                       // uniform lane idx
            ph[g] = __builtin_amdgcn_readlane(myPh, src);
            pv[g] = __builtin_amdgcn_readlane(myPv, src);
            a1[g] = __uint_as_float(__builtin_amdgcn_readlane(__float_as_uint(myA1), src));
            a2[g] = __uint_as_float(__builtin_amdgcn_readlane(__float_as_uint(myA2), src));
        }
        float wi = 0.f;
#pragma unroll
        for (int g = 0; g < GRP; ++g)
            if (kI[g] == k) wi += w3v[g];

        // ---- H pass: rows h0+i+EP always in [2,57]; col clamped+weight-masked.
        // One base address per g; 7 loads with folded immediate offsets
        // (240 B row stride, max 1440 < 4095). Lanes contiguous -> coalesced.
        const float* hrow = ch + (h0 + EP) * WIN;
#pragma unroll
        for (int g = 0; g < GRP; ++g) {
            int ix   = wc + EP + ph[g];                       // may be OOB
            float wh = ((unsigned)ix < (unsigned)WIN) ? a1[g] : 0.f;
            int ixc  = ix < 0 ? 0 : (ix > WIN - 1 ? WIN - 1 : ix);
            const float* p = hrow + ixc;
#pragma unroll
            for (int i = 0; i < ROWS_PW; ++i)
                accH[i] = fmaf(p[i * WIN], wh, accH[i]);
        }

        // ---- V pass: col cV valid; rows rb..rb+6, wave-uniform fast/slow.
#pragma unroll
        for (int g = 0; g < GRP; ++g) {
            const int rb = h0 + EP + pv[g];                   // scalar
            if (rb >= 0 && rb <= HIN - ROWS_PW) {             // fast: all rows in
                const float* p = ch + rb * WIN + cV;
#pragma unroll
                for (int i = 0; i < ROWS_PW; ++i)
                    accV[i] = fmaf(p[i * WIN], a2[g], accV[i]);
            } else {                                          // edge waves only
#pragma unroll
                for (int i = 0; i < ROWS_PW; ++i) {
                    int r    = rb + i;
                    float wv = ((unsigned)r < (unsigned)HIN) ? a2[g] : 0.f;
                    int rc   = r < 0 ? 0 : (r > HIN - 1 ? HIN - 1 : r);
                    accV[i]  = fmaf(ch[rc * WIN + cV], wv, accV[i]);
                }
            }
        }

        // ---- Identity pass (block-uniform branch)
        if (wi != 0.f) {
            const float* p = ch + (h0 + EP) * WIN + cV;
#pragma unroll
            for (int i = 0; i < ROWS_PW; ++i)
                accI[i] = fmaf(p[i * WIN], wi, accI[i]);
        }
    }

    // Epilogue: per-lane row stores (slab-store A/B in r2 showed no diff).
    if (w < WOUT) {
        const size_t OSZ  = (size_t)BATCH * C_OUT_N * HOUT * WOUT;
        const size_t base = (((size_t)b * C_OUT_N + co) * HOUT + h0) * WOUT + w;
#pragma unroll
        for (int i = 0; i < ROWS_PW; ++i) {
            out[base + (size_t)i * WOUT]           = accH[i];
            out[OSZ + base + (size_t)i * WOUT]     = accV[i];
            out[2 * OSZ + base + (size_t)i * WOUT] = accI[i];
        }
    }
}

extern "C" void kernel_launch(void* const* d_in, const int* in_sizes, int n_in,
                              void* d_out, int out_size, void* d_ws, size_t ws_size,
                              hipStream_t stream) {
    const float* x   = (const float*)d_in[0];
    const float* w1  = (const float*)d_in[1];
    const float* w2  = (const float*)d_in[2];
    const float* w3  = (const float*)d_in[3];
    const int* pad_hv      = (const int*)d_in[4];
    const int* idx_identit = (const int*)d_in[5];
    float* out = (float*)d_out;

    dim3 grid(C_OUT_N, BATCH);   // 768 blocks, 512 threads, no LDS
    dim3 block(512);
    addshift_kernel<<<grid, block, 0, stream>>>(x, w1, w2, w3, pad_hv, idx_identit, out);
}

// Round 11
// 199.730 us; speedup vs baseline: 1.1740x; 1.1740x over previous
//
#include <hip/hip_runtime.h>

// Problem constants (fixed by the reference file)
#define BATCH   8
#define C_OUT_N 96
#define NK      11
#define C_IN_N  1056      // C_OUT_N * NK
#define GRP     4
#define HOUT    56
#define WOUT    56
#define HIN     60
#define WIN     60
#define EP      2

#define CH_DW   (HIN * WIN)   // 3600 dwords per channel, contiguous
#define BUF_DW  3840          // 3600 + 240 pad for DMA tail lanes (never read)
#define ROWS_PW 7             // 8 waves x 7 rows = 56 output rows

// Address-space pointer types for global_load_lds
typedef const float __attribute__((address_space(1)))* gas1_t;
typedef float       __attribute__((address_space(3)))* las3_t;

// DMA one 3600-dword channel into LDS (linear, stride 60 rows).
// Per wave: issue0 covers float4 [wid*64, wid*64+63] (max 511 < 900),
// issue1 covers [512+wid*64, ...]; tail lanes clamp the GLOBAL src (per-lane
// src is allowed) and land in the 240-dword pad; wave 7's issue1 skipped
// (dest would exceed the buffer).
__device__ __forceinline__ void stage_chan(const float* src, float* dst, int tid)
{
    const int wid  = tid >> 6;
    const int lane = tid & 63;
    __builtin_amdgcn_global_load_lds((gas1_t)(src + (wid * 64 + lane) * 4),
                                     (las3_t)(dst + wid * 256), 16, 0, 0);
    if (wid < 7) {
        int f1 = 512 + wid * 64 + lane;
        if (f1 > 899) f1 = 899;                       // clamp src, dest -> pad
        __builtin_amdgcn_global_load_lds((gas1_t)(src + f1 * 4),
                                         (las3_t)(dst + 2048 + wid * 256), 16, 0, 0);
    }
}

// One block per (b, co); 512 threads = 8 waves; double-buffered unpadded
// channel tiles; ONE barrier per k (implicit vmcnt/lgkm drain in
// __syncthreads covers the DMA). OOB handling: H by per-g col clamp +
// weight mask; V by wave-uniform fast/slow row split (fast path keeps
// compile-time i*60 offsets -> ds_read2_b32 merging).
//
// This is the measured optimum (bench 198.63 us, kernel ~56 us). Falsified
// alternatives: counted-vmcnt triple-buffer (null), read2 offset rebase
// (null), readlane param broadcast (null), no-LDS direct-load (+62%),
// padded-tile reg-staging (+45%), mask-everything unpadded (+108%).
__global__ __launch_bounds__(512, 3) void addshift_kernel(
    const float* __restrict__ x,
    const float* __restrict__ w1,
    const float* __restrict__ w2,
    const float* __restrict__ w3,
    const int*   __restrict__ pad_hv,       // (C_IN, 8)
    const int*   __restrict__ idx_identit,  // (C_OUT, 4)
    float* __restrict__ out)                // [out_h | out_v | out_i]
{
    const int co  = blockIdx.x;
    const int b   = blockIdx.y;
    const int tid = threadIdx.x;

    __shared__ __align__(16) float buf[2][BUF_DW];   // 30720 B

    const int wave = tid >> 6;
    const int w    = tid & 63;
    const int wc   = (w < WOUT) ? w : (WOUT - 1);    // clamp idle lanes
    const int h0   = __builtin_amdgcn_readfirstlane(wave * ROWS_PW); // scalar
    const int cV   = wc + EP;                        // V/I column, always valid

    // Block-uniform identity-gather info
    int   kI[GRP];
    float w3v[GRP];
#pragma unroll
    for (int g = 0; g < GRP; ++g) {
        kI[g]  = idx_identit[co * GRP + g] - co * NK;   // in [0, NK)
        w3v[g] = w3[g * C_OUT_N + co];
    }

    float accH[ROWS_PW], accV[ROWS_PW], accI[ROWS_PW];
#pragma unroll
    for (int i = 0; i < ROWS_PW; ++i) { accH[i] = 0.f; accV[i] = 0.f; accI[i] = 0.f; }

    const float* chan_base = x + ((size_t)b * C_IN_N + (size_t)co * NK) * CH_DW;

    // Prologue: DMA channel 0 into buf0.
    stage_chan(chan_base, buf[0], tid);

#pragma unroll 1
    for (int k = 0; k < NK; ++k) {
        // Single barrier per k: compiler emits s_waitcnt vmcnt(0) lgkmcnt(0)
        // before s_barrier -> DMA of channel k complete in ALL waves, and all
        // waves are done reading the buffer we are about to re-stage.
        __syncthreads();

        if (k + 1 < NK)
            stage_chan(chan_base + (size_t)(k + 1) * CH_DW, buf[(k + 1) & 1], tid);

        const float* __restrict__ bf = buf[k & 1];

        const int c = co * NK + k;
        int ph[GRP], pv[GRP];
        float a1[GRP], a2[GRP];
#pragma unroll
        for (int g = 0; g < GRP; ++g) {
            ph[g] = pad_hv[c * 8 + g];
            pv[g] = pad_hv[c * 8 + 4 + g];
            a1[g] = w1[g * C_IN_N + c];
            a2[g] = w2[g * C_IN_N + c];
        }
        float wi = 0.f;
#pragma unroll
        for (int g = 0; g < GRP; ++g)
            if (kI[g] == k) wi += w3v[g];

        // ---- H pass: rows h0+i+EP always valid; col clamped + weight-masked.
        const float* hrow = bf + (h0 + EP) * WIN;
#pragma unroll
        for (int g = 0; g < GRP; ++g) {
            int ix   = wc + EP + ph[g];                       // may be OOB
            float wh = ((unsigned)ix < (unsigned)WIN) ? a1[g] : 0.f;
            int ixc  = ix < 0 ? 0 : (ix > WIN - 1 ? WIN - 1 : ix);
            const float* p = hrow + ixc;
#pragma unroll
            for (int i = 0; i < ROWS_PW; ++i)
                accH[i] = fmaf(p[i * WIN], wh, accH[i]);
        }

        // ---- V pass: col cV valid; rows rb..rb+6, wave-uniform fast/slow.
#pragma unroll
        for (int g = 0; g < GRP; ++g) {
            const int rb = h0 + EP + pv[g];                   // scalar
            if (rb >= 0 && rb <= HIN - ROWS_PW) {             // fast: all rows in
                const float* p = bf + rb * WIN + cV;
#pragma unroll
                for (int i = 0; i < ROWS_PW; ++i)
                    accV[i] = fmaf(p[i * WIN], a2[g], accV[i]);
            } else {                                          // edge waves only
#pragma unroll
                for (int i = 0; i < ROWS_PW; ++i) {
                    int r    = rb + i;
                    float wv = ((unsigned)r < (unsigned)HIN) ? a2[g] : 0.f;
                    int rc   = r < 0 ? 0 : (r > HIN - 1 ? HIN - 1 : r);
                    accV[i]  = fmaf(bf[rc * WIN + cV], wv, accV[i]);
                }
            }
        }

        // ---- Identity pass (block-uniform branch)
        if (wi != 0.f) {
            const float* p = bf + (h0 + EP) * WIN + cV;
#pragma unroll
            for (int i = 0; i < ROWS_PW; ++i)
                accI[i] = fmaf(p[i * WIN], wi, accI[i]);
        }
    }

    // Epilogue: per-lane row stores (slab-store A/B in r2 showed no diff).
    if (w < WOUT) {
        const size_t OSZ  = (size_t)BATCH * C_OUT_N * HOUT * WOUT;
        const size_t base = (((size_t)b * C_OUT_N + co) * HOUT + h0) * WOUT + w;
#pragma unroll
        for (int i = 0; i < ROWS_PW; ++i) {
            out[base + (size_t)i * WOUT]           = accH[i];
            out[OSZ + base + (size_t)i * WOUT]     = accV[i];
            out[2 * OSZ + base + (size_t)i * WOUT] = accI[i];
        }
    }
}

extern "C" void kernel_launch(void* const* d_in, const int* in_sizes, int n_in,
                              void* d_out, int out_size, void* d_ws, size_t ws_size,
                              hipStream_t stream) {
    const float* x   = (const float*)d_in[0];
    const float* w1  = (const float*)d_in[1];
    const float* w2  = (const float*)d_in[2];
    const float* w3  = (const float*)d_in[3];
    const int* pad_hv      = (const int*)d_in[4];
    const int* idx_identit = (const int*)d_in[5];
    float* out = (float*)d_out;

    dim3 grid(C_OUT_N, BATCH);   // 768 blocks, 512 threads
    dim3 block(512);
    addshift_kernel<<<grid, block, 0, stream>>>(x, w1, w2, w3, pad_hv, idx_identit, out);
}